// Round 1
// baseline (464.497 us; speedup 1.0000x reference)
//
#include <hip/hip_runtime.h>

// Problem constants (VEConv): E=800000 edges, N=50000 nodes, RBF=100, D=64.
// E % 64 == 0 (12500 blocks of 64 edges), so no partial-tile guards needed.
#define RBF_DIM 100
#define K1 128   // padded K for GEMM1 (col 100 = bias-1.0 trick, 101..127 = 0)

typedef __attribute__((ext_vector_type(8))) short bf16x8;
typedef __attribute__((ext_vector_type(4))) float f32x4;

__device__ __forceinline__ unsigned short f2bf(float f) {
    union { float f; unsigned int u; } v; v.f = f;
    unsigned int r = (v.u + 0x7FFFu + ((v.u >> 16) & 1u)) >> 16;
    return (unsigned short)r;
}

// ---- pre-kernel: transposed bf16 weights into ws ----
// ws layout (ushort): [0,8192) W1T[64][128]  (k=100 -> b1, k>100 -> 0)
//                     [8192,12288) W2T[64][64]
//                     [12288,16384) W3T[64][64]
__global__ void prep_weights(const float* __restrict__ W1, const float* __restrict__ b1,
                             const float* __restrict__ W2, const float* __restrict__ W3,
                             unsigned short* __restrict__ ws) {
    int t = threadIdx.x;
    for (int idx = t; idx < 64 * 128; idx += 256) {
        int o = idx >> 7, k = idx & 127;
        float v = (k < RBF_DIM) ? W1[k * 64 + o] : ((k == RBF_DIM) ? b1[o] : 0.0f);
        ws[idx] = f2bf(v);
    }
    for (int idx = t; idx < 64 * 64; idx += 256) {
        int o = idx >> 6, k = idx & 63;
        ws[8192 + idx]  = f2bf(W2[k * 64 + o]);
        ws[12288 + idx] = f2bf(W3[k * 64 + o]);
    }
}

// ---- main fused kernel: 64 edges per block, 4 waves x 16 edges ----
__global__ __launch_bounds__(256, 2)
void veconv_main(const float* __restrict__ rbf, const float* __restrict__ edge_f,
                 const float* __restrict__ node,
                 const float* __restrict__ b2, const float* __restrict__ b3,
                 const int* __restrict__ src, const int* __restrict__ dst,
                 const unsigned short* __restrict__ wsw,
                 float* __restrict__ out) {
    // LDS: all tiles XOR-swizzled to break the [row][64/128] same-bank pattern (G4).
    __shared__ unsigned short rbf_lds[64 * 128]; // bf16, [e][k^((e&7)<<3)]
    __shared__ unsigned short ef_lds[64 * 64];   // bf16
    __shared__ unsigned short sp_lds[4 * 16 * 64]; // bf16, per-wave softplus output
    __shared__ float h_lds[64 * 64];             // f32, [e][d^((e&7)<<2)]
    __shared__ float en_lds[64 * 64];

    const int tid = threadIdx.x;
    const int lane = tid & 63, wid = tid >> 6;
    const int l15 = lane & 15, g = lane >> 4;
    const long e0 = (long)blockIdx.x * 64;

    // ---- stage rbf: 64 x 100 f32 -> bf16 [64][128] swizzled, + bias column ----
    for (int i = 0; i < 7; ++i) {
        int idx4 = tid + 256 * i;           // 1600 float4 total (25 per row)
        if (idx4 < 1600) {
            int row = idx4 / 25;
            int q = idx4 - row * 25;
            const float4 v = *(const float4*)(rbf + (e0 + row) * RBF_DIM + 4 * q);
            int el = row * 128 + ((4 * q) ^ ((row & 7) << 3));
            unsigned int p0 = (unsigned int)f2bf(v.x) | ((unsigned int)f2bf(v.y) << 16);
            unsigned int p1 = (unsigned int)f2bf(v.z) | ((unsigned int)f2bf(v.w) << 16);
            *(uint2*)&rbf_lds[el] = make_uint2(p0, p1);
        }
        int idx = tid + 256 * i;            // pad cols 100..127 (1792 elems)
        if (idx < 64 * 28) {
            int row = idx / 28;
            int kk = 100 + (idx - row * 28);
            rbf_lds[row * 128 + (kk ^ ((row & 7) << 3))] =
                (kk == RBF_DIM) ? (unsigned short)0x3F80 : (unsigned short)0; // 1.0 -> bias row
        }
    }
    // ---- stage edge_f: 64 x 64 f32 -> bf16 swizzled ----
    for (int i = 0; i < 4; ++i) {
        int idx4 = tid + 256 * i;           // 1024 float4 (16 per row)
        int row = idx4 >> 4;
        int q = idx4 & 15;
        const float4 v = *(const float4*)(edge_f + (e0 + row) * 64 + 4 * q);
        int el = row * 64 + ((4 * q) ^ ((row & 7) << 3));
        unsigned int p0 = (unsigned int)f2bf(v.x) | ((unsigned int)f2bf(v.y) << 16);
        unsigned int p1 = (unsigned int)f2bf(v.z) | ((unsigned int)f2bf(v.w) << 16);
        *(uint2*)&ef_lds[el] = make_uint2(p0, p1);
    }

    // ---- weight A-fragments in registers (lane m = l15 -> out row 16*t+l15, k slice 8*g) ----
    bf16x8 w1f[4][4], w2f[4][2], w3f[4][2];
    for (int t4 = 0; t4 < 4; ++t4) {
        for (int ks = 0; ks < 4; ++ks)
            w1f[t4][ks] = *(const bf16x8*)(wsw + (16 * t4 + l15) * 128 + 32 * ks + 8 * g);
        for (int ks = 0; ks < 2; ++ks) {
            w2f[t4][ks] = *(const bf16x8*)(wsw + 8192  + (16 * t4 + l15) * 64 + 32 * ks + 8 * g);
            w3f[t4][ks] = *(const bf16x8*)(wsw + 12288 + (16 * t4 + l15) * 64 + 32 * ks + 8 * g);
        }
    }
    const float b2l = b2[lane], b3l = b3[lane];

    __syncthreads();

    const int brow = 16 * wid + l15;        // this lane's edge row (B-operand col)
    const int swz = (l15 & 7) << 3;         // bf16 k-swizzle key (brow&7 == l15&7)

    // ---- GEMM1: D1[out][e] = W1T @ rbf^T  (swapped; B^T rows = natural rbf rows) ----
    f32x4 acc1[4];
    for (int t4 = 0; t4 < 4; ++t4) acc1[t4] = (f32x4){0.f, 0.f, 0.f, 0.f};
    for (int ks = 0; ks < 4; ++ks) {
        bf16x8 bf = *(const bf16x8*)&rbf_lds[brow * 128 + ((32 * ks + 8 * g) ^ swz)];
        for (int t4 = 0; t4 < 4; ++t4)
            acc1[t4] = __builtin_amdgcn_mfma_f32_16x16x32_bf16(w1f[t4][ks], bf, acc1[t4], 0, 0, 0);
    }

    // ---- softplus(beta=0.5, thr=14) in-register; write sp[e][k] bf16 (swizzled) ----
    // C-layout: lane holds col e=l15, rows out = 16*t4 + 4*g + r  (verified m89/m91)
    for (int t4 = 0; t4 < 4; ++t4) {
        float spv[4];
        for (int r = 0; r < 4; ++r) {
            float x = acc1[t4][r];
            float bx = 0.5f * x;
            float s = 2.0f * __logf(1.0f + __expf(bx));
            spv[r] = (bx > 14.0f) ? x : s;
        }
        unsigned int p0 = (unsigned int)f2bf(spv[0]) | ((unsigned int)f2bf(spv[1]) << 16);
        unsigned int p1 = (unsigned int)f2bf(spv[2]) | ((unsigned int)f2bf(spv[3]) << 16);
        int el = (wid * 16 + l15) * 64 + ((16 * t4 + 4 * g) ^ swz);
        *(uint2*)&sp_lds[el] = make_uint2(p0, p1);
    }

    // ---- GEMM2: h = W2T @ sp^T, GEMM3: en = W3T @ edge_f^T ----
    f32x4 acc2[4], acc3[4];
    for (int t4 = 0; t4 < 4; ++t4) {
        acc2[t4] = (f32x4){0.f, 0.f, 0.f, 0.f};
        acc3[t4] = (f32x4){0.f, 0.f, 0.f, 0.f};
    }
    for (int ks = 0; ks < 2; ++ks) {
        bf16x8 bsp = *(const bf16x8*)&sp_lds[(wid * 16 + l15) * 64 + ((32 * ks + 8 * g) ^ swz)];
        bf16x8 bef = *(const bf16x8*)&ef_lds[brow * 64 + ((32 * ks + 8 * g) ^ swz)];
        for (int t4 = 0; t4 < 4; ++t4) {
            acc2[t4] = __builtin_amdgcn_mfma_f32_16x16x32_bf16(w2f[t4][ks], bsp, acc2[t4], 0, 0, 0);
            acc3[t4] = __builtin_amdgcn_mfma_f32_16x16x32_bf16(w3f[t4][ks], bef, acc3[t4], 0, 0, 0);
        }
    }

    // ---- transpose h/en via swizzled LDS (f32, 4-word swizzle) ----
    const int swz2 = (l15 & 7) << 2;
    for (int t4 = 0; t4 < 4; ++t4) {
        int col = (16 * t4 + 4 * g) ^ swz2;
        *(f32x4*)&h_lds[brow * 64 + col]  = acc2[t4];
        *(f32x4*)&en_lds[brow * 64 + col] = acc3[t4];
    }

    // ---- epilogue: per edge, coalesced node-gather + atomic scatter (lane = dim) ----
    for (int ee = 0; ee < 16; ++ee) {
        int e_loc = 16 * wid + ee;          // rows this wave wrote itself (no barrier)
        long eg = e0 + e_loc;
        int s = src[eg], d = dst[eg];       // wave-uniform -> scalar loads
        int col = lane ^ ((ee & 7) << 2);   // (e_loc&7)==(ee&7)
        float h  = h_lds[e_loc * 64 + col]  + b2l;
        float en = en_lds[e_loc * 64 + col] + b3l;
        float nd = node[(long)s * 64 + lane];
        atomicAdd(&out[(long)d * 64 + lane], nd * h + en);
    }
}

extern "C" void kernel_launch(void* const* d_in, const int* in_sizes, int n_in,
                              void* d_out, int out_size, void* d_ws, size_t ws_size,
                              hipStream_t stream) {
    const float* rbf    = (const float*)d_in[0];
    const float* edge_f = (const float*)d_in[1];
    const float* node   = (const float*)d_in[2];
    const float* W1     = (const float*)d_in[3];
    const float* b1     = (const float*)d_in[4];
    const float* W2     = (const float*)d_in[5];
    const float* b2     = (const float*)d_in[6];
    const float* W3     = (const float*)d_in[7];
    const float* b3     = (const float*)d_in[8];
    const int*   src    = (const int*)d_in[9];
    const int*   dst    = (const int*)d_in[10];
    float* out = (float*)d_out;
    unsigned short* ws = (unsigned short*)d_ws;

    const int E = in_sizes[9];              // 800000, divisible by 64

    hipMemsetAsync(d_out, 0, (size_t)out_size * sizeof(float), stream);
    prep_weights<<<1, 256, 0, stream>>>(W1, b1, W2, W3, ws);
    veconv_main<<<E / 64, 256, 0, stream>>>(rbf, edge_f, node, b2, b3, src, dst, ws, out);
}